// Round 1
// baseline (1086.779 us; speedup 1.0000x reference)
//
#include <hip/hip_runtime.h>
#include <math.h>

#define N_NODES 51200
#define N_EDGES 819200
#define NB 64

__device__ __forceinline__ float eluf(float x) {
  return x > 0.f ? x : expm1f(x);
}

// Bilinear spline basis for edge e: 4 corners, weights + weight-matrix index.
__device__ __forceinline__ void edge_basis(const float* __restrict__ pseudo, int e,
                                           float bas[4], int kidx[4]) {
  float v0 = pseudo[2 * e] * 4.f;
  float v1 = pseudo[2 * e + 1] * 4.f;
  int lo0 = min(max((int)floorf(v0), 0), 3);
  int lo1 = min(max((int)floorf(v1), 0), 3);
  float f0 = v0 - (float)lo0, f1 = v1 - (float)lo1;
  float g0 = 1.f - f0, g1 = 1.f - f1;
  bas[0] = g0 * g1; kidx[0] = lo0 * 5 + lo1;
  bas[1] = g0 * f1; kidx[1] = lo0 * 5 + lo1 + 1;
  bas[2] = f0 * g1; kidx[2] = (lo0 + 1) * 5 + lo1;
  bas[3] = f0 * f1; kidx[3] = (lo0 + 1) * 5 + lo1 + 1;
}

// Layer-1 scatter: T1[dst][k][i] += basis * x[src][i]   (i<7), plus deg count.
// 32 lanes per edge: lane = s*8 + i (4 idle i==7 lanes; lane31 does deg).
__global__ __launch_bounds__(256) void scatter1(const float* __restrict__ x,
                                                const int* __restrict__ ei,
                                                const float* __restrict__ pseudo,
                                                float* __restrict__ T1,
                                                float* __restrict__ deg) {
  int tid = threadIdx.x;
  int e = blockIdx.x * 8 + (tid >> 5);
  int l = tid & 31;
  int src = ei[e], dst = ei[N_EDGES + e];
  float bas[4]; int kidx[4];
  edge_basis(pseudo, e, bas, kidx);
  int s = l >> 3, i = l & 7;
  if (i < 7) {
    atomicAdd(&T1[(dst * 25 + kidx[s]) * 7 + i], bas[s] * x[src * 7 + i]);
  } else if (s == 3) {
    atomicAdd(&deg[dst], 1.0f);
  }
}

// Layer-1 GEMM: h1 = elu( T1(n,175) @ W1(175,32) / deg + x @ root1 + b1 )
// block: 256 thr, tile 32 rows x 32 cols, thread = (o, rq), 4 rows each.
__global__ __launch_bounds__(256) void gemm1(const float* __restrict__ T1,
                                             const float* __restrict__ W1,
                                             const float* __restrict__ x,
                                             const float* __restrict__ root1,
                                             const float* __restrict__ b1,
                                             const float* __restrict__ deg,
                                             float* __restrict__ h1) {
  __shared__ float Wl[175 * 32];
  __shared__ float Tl[32 * 176];
  __shared__ float r1l[7 * 32];
  __shared__ float b1l[32];
  int tid = threadIdx.x;
  int n0 = blockIdx.x * 32;
  for (int idx = tid; idx < 175 * 32; idx += 256) Wl[idx] = W1[idx];
  for (int idx = tid; idx < 32 * 175; idx += 256) {
    int r = idx / 175, kk = idx - r * 175;
    Tl[r * 176 + kk] = T1[(n0 + r) * 175 + kk];
  }
  if (tid < 224) r1l[tid] = root1[tid];
  if (tid < 32) b1l[tid] = b1[tid];
  __syncthreads();
  int o = tid & 31, rq = tid >> 5;
  float acc[4] = {0.f, 0.f, 0.f, 0.f};
  for (int ki = 0; ki < 175; ki++) {
    float w = Wl[ki * 32 + o];
#pragma unroll
    for (int j = 0; j < 4; j++) acc[j] += Tl[(j * 8 + rq) * 176 + ki] * w;
  }
#pragma unroll
  for (int j = 0; j < 4; j++) {
    int n = n0 + j * 8 + rq;
    float dv = fmaxf(deg[n], 1.f);
    float v = acc[j] / dv + b1l[o];
#pragma unroll
    for (int i = 0; i < 7; i++) v += x[n * 7 + i] * r1l[i * 32 + o];
    h1[n * 32 + o] = eluf(v);
  }
}

// Layer-2 scatter: T2[dst][k][i] += basis * h1[src][i]  (i<32). 32 lanes/edge.
__global__ __launch_bounds__(256) void scatter2(const float* __restrict__ h1,
                                                const int* __restrict__ ei,
                                                const float* __restrict__ pseudo,
                                                float* __restrict__ T2) {
  int tid = threadIdx.x;
  int e = blockIdx.x * 8 + (tid >> 5);
  int l = tid & 31;
  int src = ei[e], dst = ei[N_EDGES + e];
  float bas[4]; int kidx[4];
  edge_basis(pseudo, e, bas, kidx);
  float h = h1[src * 32 + l];
#pragma unroll
  for (int s = 0; s < 4; s++)
    atomicAdd(&T2[(dst * 25 + kidx[s]) * 32 + l], bas[s] * h);
}

// Layer-2 GEMM: h2 = elu( T2(n,800) @ W2(800,64) / deg + h1 @ root2 + b2 )
// block: 256 thr, tile 64x64, thread-tile 4x4, K-tiles of 32.
__global__ __launch_bounds__(256) void gemm2(const float* __restrict__ T2,
                                             const float* __restrict__ W2,
                                             const float* __restrict__ h1,
                                             const float* __restrict__ root2,
                                             const float* __restrict__ b2,
                                             const float* __restrict__ deg,
                                             float* __restrict__ h2) {
  __shared__ __align__(16) float Tt[64 * 33];
  __shared__ __align__(16) float Wt[32 * 64];
  int tid = threadIdx.x;
  int n0 = blockIdx.x * 64;
  int to = tid & 15, tr = tid >> 4;
  int o4 = to * 4, r4 = tr * 4;
  float acc[4][4] = {};
  for (int kt = 0; kt < 25; kt++) {
    __syncthreads();
    {
      int kk = tid & 31, r = tid >> 5;
      for (int rr = r; rr < 64; rr += 8)
        Tt[rr * 33 + kk] = T2[(n0 + rr) * 800 + kt * 32 + kk];
      int oo = tid & 63, k4 = tid >> 6;
      for (int kk3 = k4; kk3 < 32; kk3 += 4)
        Wt[kk3 * 64 + oo] = W2[(kt * 32 + kk3) * 64 + oo];
    }
    __syncthreads();
#pragma unroll 8
    for (int kk = 0; kk < 32; kk++) {
      float4 w = *(const float4*)&Wt[kk * 64 + o4];
#pragma unroll
      for (int j = 0; j < 4; j++) {
        float t = Tt[(r4 + j) * 33 + kk];
        acc[j][0] += t * w.x; acc[j][1] += t * w.y;
        acc[j][2] += t * w.z; acc[j][3] += t * w.w;
      }
    }
  }
  // epilogue: + h1(n,32) @ root2(32,64), /deg, +b2, elu
  __syncthreads();
  {
    int i = tid & 31, r = tid >> 5;
    for (int rr = r; rr < 64; rr += 8)
      Tt[rr * 33 + i] = h1[(n0 + rr) * 32 + i];
    int oo = tid & 63, k4 = tid >> 6;
    for (int i2 = k4; i2 < 32; i2 += 4)
      Wt[i2 * 64 + oo] = root2[i2 * 64 + oo];
  }
  __syncthreads();
  float acc2[4][4] = {};
  for (int i = 0; i < 32; i++) {
    float4 w = *(const float4*)&Wt[i * 64 + o4];
#pragma unroll
    for (int j = 0; j < 4; j++) {
      float t = Tt[(r4 + j) * 33 + i];
      acc2[j][0] += t * w.x; acc2[j][1] += t * w.y;
      acc2[j][2] += t * w.z; acc2[j][3] += t * w.w;
    }
  }
#pragma unroll
  for (int j = 0; j < 4; j++) {
    int n = n0 + r4 + j;
    float dv = fmaxf(deg[n], 1.f);
    float4 outv;
    float* ov = (float*)&outv;
#pragma unroll
    for (int jj = 0; jj < 4; jj++)
      ov[jj] = eluf(acc[j][jj] / dv + acc2[j][jj] + b2[o4 + jj]);
    *(float4*)&h2[n * 64 + o4] = outv;
  }
}

// Mean-pool h2 over each slice range -> gbuf[g][64]
__global__ __launch_bounds__(256) void pool(const float* __restrict__ h2,
                                            const int* __restrict__ slices,
                                            float* __restrict__ gbuf) {
  int g = blockIdx.x;
  int tid = threadIdx.x;
  int o = tid & 63, q = tid >> 6;
  int s0 = slices[g], s1 = slices[g + 1];
  float p = 0.f;
  for (int n = s0 + q; n < s1; n += 4) p += h2[n * 64 + o];
  __shared__ float red[4][64];
  red[q][o] = p;
  __syncthreads();
  if (q == 0) {
    float s = red[0][o] + red[1][o] + red[2][o] + red[3][o];
    float cnt = (float)(s1 - s0);
    gbuf[g * 64 + o] = s / fmaxf(cnt, 1.f);
  }
}

// FC(64->30) + log_softmax. One block (64 thr) per group; lanes 0..29 active.
__global__ __launch_bounds__(64) void fc_ls(const float* __restrict__ gbuf,
                                            const float* __restrict__ fcw,
                                            const float* __restrict__ fcb,
                                            float* __restrict__ out) {
  int g = blockIdx.x;
  int l = threadIdx.x;
  float logit = -INFINITY;
  if (l < 30) {
    float acc = fcb[l];
    for (int i = 0; i < 64; i++) acc += gbuf[g * 64 + i] * fcw[i * 30 + l];
    logit = acc;
  }
  float m = logit;
  for (int off = 16; off; off >>= 1) m = fmaxf(m, __shfl_xor(m, off, 32));
  float e = (l < 30) ? expf(logit - m) : 0.f;
  for (int off = 16; off; off >>= 1) e += __shfl_xor(e, off, 32);
  if (l < 30) out[g * 30 + l] = logit - m - logf(e);
}

extern "C" void kernel_launch(void* const* d_in, const int* in_sizes, int n_in,
                              void* d_out, int out_size, void* d_ws, size_t ws_size,
                              hipStream_t stream) {
  const float* x      = (const float*)d_in[0];
  const int*   ei     = (const int*)d_in[1];
  const float* pseudo = (const float*)d_in[2];
  const int*   slices = (const int*)d_in[3];
  const float* W1     = (const float*)d_in[4];
  const float* root1  = (const float*)d_in[5];
  const float* b1     = (const float*)d_in[6];
  const float* W2     = (const float*)d_in[7];
  const float* root2  = (const float*)d_in[8];
  const float* b2     = (const float*)d_in[9];
  const float* fcw    = (const float*)d_in[10];
  const float* fcb    = (const float*)d_in[11];
  float* out = (float*)d_out;

  float* ws   = (float*)d_ws;
  float* deg  = ws;                                  // N
  float* T1   = deg + N_NODES;                       // N*175
  float* T2   = T1 + (size_t)N_NODES * 175;          // N*800
  float* h1   = T2 + (size_t)N_NODES * 800;          // N*32
  float* h2   = h1 + (size_t)N_NODES * 32;           // N*64
  float* gbuf = h2 + (size_t)N_NODES * 64;           // 64*64

  // zero deg + T1 + T2 (contiguous)
  size_t zero_bytes = (size_t)N_NODES * (1 + 175 + 800) * sizeof(float);
  hipMemsetAsync(d_ws, 0, zero_bytes, stream);

  scatter1<<<N_EDGES / 8, 256, 0, stream>>>(x, ei, pseudo, T1, deg);
  gemm1<<<N_NODES / 32, 256, 0, stream>>>(T1, W1, x, root1, b1, deg, h1);
  scatter2<<<N_EDGES / 8, 256, 0, stream>>>(h1, ei, pseudo, T2);
  gemm2<<<N_NODES / 64, 256, 0, stream>>>(T2, W2, h1, root2, b2, deg, h2);
  pool<<<NB, 256, 0, stream>>>(h2, slices, gbuf);
  fc_ls<<<NB, 64, 0, stream>>>(gbuf, fcw, fcb, out);
}

// Round 2
// 685.462 us; speedup vs baseline: 1.5855x; 1.5855x over previous
//
#include <hip/hip_runtime.h>
#include <hip/hip_bf16.h>
#include <math.h>

#define N_NODES 51200
#define N_EDGES 819200
#define NB 64

__device__ __forceinline__ float eluf(float x) {
  return x > 0.f ? x : expm1f(x);
}

// Bilinear spline basis for edge e: 4 corners, weights + weight-matrix index.
__device__ __forceinline__ void edge_basis(const float* __restrict__ pseudo, int e,
                                           float bas[4], int kidx[4]) {
  float v0 = pseudo[2 * e] * 4.f;
  float v1 = pseudo[2 * e + 1] * 4.f;
  int lo0 = min(max((int)floorf(v0), 0), 3);
  int lo1 = min(max((int)floorf(v1), 0), 3);
  float f0 = v0 - (float)lo0, f1 = v1 - (float)lo1;
  float g0 = 1.f - f0, g1 = 1.f - f1;
  bas[0] = g0 * g1; kidx[0] = lo0 * 5 + lo1;
  bas[1] = g0 * f1; kidx[1] = lo0 * 5 + lo1 + 1;
  bas[2] = f0 * g1; kidx[2] = (lo0 + 1) * 5 + lo1;
  bas[3] = f0 * f1; kidx[3] = (lo0 + 1) * 5 + lo1 + 1;
}

// Layer-1 scatter: T1[dst][k][i] += basis * x[src][i]   (i<7), plus deg count.
// 32 lanes per edge: lane = s*8 + i (4 idle i==7 lanes; lane31 does deg).
__global__ __launch_bounds__(256) void scatter1(const float* __restrict__ x,
                                                const int* __restrict__ ei,
                                                const float* __restrict__ pseudo,
                                                float* __restrict__ T1,
                                                float* __restrict__ deg) {
  int tid = threadIdx.x;
  int e = blockIdx.x * 8 + (tid >> 5);
  int l = tid & 31;
  int src = ei[e], dst = ei[N_EDGES + e];
  float bas[4]; int kidx[4];
  edge_basis(pseudo, e, bas, kidx);
  int s = l >> 3, i = l & 7;
  if (i < 7) {
    atomicAdd(&T1[(dst * 25 + kidx[s]) * 7 + i], bas[s] * x[src * 7 + i]);
  } else if (s == 3) {
    atomicAdd(&deg[dst], 1.0f);
  }
}

// Layer-1 GEMM: h1 = elu( T1(n,175) @ W1(175,32) / deg + x @ root1 + b1 )
__global__ __launch_bounds__(256) void gemm1(const float* __restrict__ T1,
                                             const float* __restrict__ W1,
                                             const float* __restrict__ x,
                                             const float* __restrict__ root1,
                                             const float* __restrict__ b1,
                                             const float* __restrict__ deg,
                                             float* __restrict__ h1) {
  __shared__ float Wl[175 * 32];
  __shared__ float Tl[32 * 176];
  __shared__ float r1l[7 * 32];
  __shared__ float b1l[32];
  int tid = threadIdx.x;
  int n0 = blockIdx.x * 32;
  for (int idx = tid; idx < 175 * 32; idx += 256) Wl[idx] = W1[idx];
  for (int idx = tid; idx < 32 * 175; idx += 256) {
    int r = idx / 175, kk = idx - r * 175;
    Tl[r * 176 + kk] = T1[(n0 + r) * 175 + kk];
  }
  if (tid < 224) r1l[tid] = root1[tid];
  if (tid < 32) b1l[tid] = b1[tid];
  __syncthreads();
  int o = tid & 31, rq = tid >> 5;
  float acc[4] = {0.f, 0.f, 0.f, 0.f};
  for (int ki = 0; ki < 175; ki++) {
    float w = Wl[ki * 32 + o];
#pragma unroll
    for (int j = 0; j < 4; j++) acc[j] += Tl[(j * 8 + rq) * 176 + ki] * w;
  }
#pragma unroll
  for (int j = 0; j < 4; j++) {
    int n = n0 + j * 8 + rq;
    float dv = fmaxf(deg[n], 1.f);
    float v = acc[j] / dv + b1l[o];
#pragma unroll
    for (int i = 0; i < 7; i++) v += x[n * 7 + i] * r1l[i * 32 + o];
    h1[n * 32 + o] = eluf(v);
  }
}

// Z[k][n][o] = sum_i h1[n][i] * W2[k][i][o], stored bf16, k-major.
// grid: (N/256, 25). Block loads 256 h1 rows (32 KB) + one W2 slice (8 KB).
__global__ __launch_bounds__(256) void gemmZ(const float* __restrict__ h1,
                                             const float* __restrict__ W2,
                                             __hip_bfloat16* __restrict__ Z) {
  __shared__ __align__(16) float Hs[256 * 32];
  __shared__ __align__(16) float Ws[32 * 64];
  int tid = threadIdx.x;
  int k = blockIdx.y;
  int n0 = blockIdx.x * 256;
  {
    const float4* s4 = (const float4*)(h1 + (size_t)n0 * 32);
    float4* h4 = (float4*)Hs;
    for (int idx = tid; idx < 2048; idx += 256) h4[idx] = s4[idx];
    const float4* w4 = (const float4*)(W2 + k * 2048);
    float4* d4 = (float4*)Ws;
    if (tid < 512) d4[tid] = w4[tid];
    if (tid + 256 < 512) {}  // (handled by the single pass below)
  }
  __syncthreads();
  int o = tid & 63, w = tid >> 6;
  float wreg[32];
#pragma unroll
  for (int i = 0; i < 32; i++) wreg[i] = Ws[i * 64 + o];
  __hip_bfloat16* zrow = Z + ((size_t)k * N_NODES + n0) * 64 + o;
  for (int r = w; r < 256; r += 4) {
    const float* hr = &Hs[r * 32];
    float acc = 0.f;
#pragma unroll
    for (int i = 0; i < 32; i++) acc += hr[i] * wreg[i];
    zrow[(size_t)r * 64] = __float2bfloat16(acc);
  }
}

// gather2: one wave per edge. msg[o] = sum_s bas_s * Z[k_s][src][o];
// agg[dst][o] += msg[o] (single 64-lane fp32 atomic row add).
__global__ __launch_bounds__(256) void gather2(const __hip_bfloat16* __restrict__ Z,
                                               const int* __restrict__ ei,
                                               const float* __restrict__ pseudo,
                                               float* __restrict__ agg) {
  int e = blockIdx.x * 4 + (threadIdx.x >> 6);
  int o = threadIdx.x & 63;
  int src = ei[e], dst = ei[N_EDGES + e];
  float bas[4]; int kidx[4];
  edge_basis(pseudo, e, bas, kidx);
  float m = 0.f;
#pragma unroll
  for (int s = 0; s < 4; s++)
    m += bas[s] * __bfloat162float(Z[((size_t)kidx[s] * N_NODES + src) * 64 + o]);
  atomicAdd(&agg[(size_t)dst * 64 + o], m);
}

// epilogue: h2 = elu(agg/deg + h1 @ root2 + b2). grid N/32, block 256.
__global__ __launch_bounds__(256) void epi2(const float* __restrict__ agg,
                                            const float* __restrict__ h1,
                                            const float* __restrict__ root2,
                                            const float* __restrict__ b2,
                                            const float* __restrict__ deg,
                                            float* __restrict__ h2) {
  __shared__ __align__(16) float Hs[32 * 32];
  __shared__ __align__(16) float Rs[32 * 64];
  __shared__ float Bs[64];
  int tid = threadIdx.x;
  int n0 = blockIdx.x * 32;
  {
    const float4* s4 = (const float4*)(h1 + (size_t)n0 * 32);
    float4* h4 = (float4*)Hs;
    if (tid < 256) h4[tid] = s4[tid];
    const float4* r4 = (const float4*)root2;
    float4* d4 = (float4*)Rs;
    for (int idx = tid; idx < 512; idx += 256) d4[idx] = r4[idx];
    if (tid < 64) Bs[tid] = b2[tid];
  }
  __syncthreads();
  int o = tid & 63, w = tid >> 6;
  for (int r = w; r < 32; r += 4) {
    int n = n0 + r;
    float acc = agg[(size_t)n * 64 + o] / fmaxf(deg[n], 1.f) + Bs[o];
    const float* hr = &Hs[r * 32];
#pragma unroll
    for (int i = 0; i < 32; i++) acc += hr[i] * Rs[i * 64 + o];
    h2[(size_t)n * 64 + o] = eluf(acc);
  }
}

// Mean-pool h2 over each slice range -> gbuf[g][64]
__global__ __launch_bounds__(256) void pool(const float* __restrict__ h2,
                                            const int* __restrict__ slices,
                                            float* __restrict__ gbuf) {
  int g = blockIdx.x;
  int tid = threadIdx.x;
  int o = tid & 63, q = tid >> 6;
  int s0 = slices[g], s1 = slices[g + 1];
  float p = 0.f;
  for (int n = s0 + q; n < s1; n += 4) p += h2[(size_t)n * 64 + o];
  __shared__ float red[4][64];
  red[q][o] = p;
  __syncthreads();
  if (q == 0) {
    float s = red[0][o] + red[1][o] + red[2][o] + red[3][o];
    float cnt = (float)(s1 - s0);
    gbuf[g * 64 + o] = s / fmaxf(cnt, 1.f);
  }
}

// FC(64->30) + log_softmax. One block (64 thr) per group; lanes 0..29 active.
__global__ __launch_bounds__(64) void fc_ls(const float* __restrict__ gbuf,
                                            const float* __restrict__ fcw,
                                            const float* __restrict__ fcb,
                                            float* __restrict__ out) {
  int g = blockIdx.x;
  int l = threadIdx.x;
  float logit = -INFINITY;
  if (l < 30) {
    float acc = fcb[l];
    for (int i = 0; i < 64; i++) acc += gbuf[g * 64 + i] * fcw[i * 30 + l];
    logit = acc;
  }
  float m = logit;
  for (int off = 16; off; off >>= 1) m = fmaxf(m, __shfl_xor(m, off, 32));
  float e = (l < 30) ? expf(logit - m) : 0.f;
  for (int off = 16; off; off >>= 1) e += __shfl_xor(e, off, 32);
  if (l < 30) out[g * 30 + l] = logit - m - logf(e);
}

extern "C" void kernel_launch(void* const* d_in, const int* in_sizes, int n_in,
                              void* d_out, int out_size, void* d_ws, size_t ws_size,
                              hipStream_t stream) {
  const float* x      = (const float*)d_in[0];
  const int*   ei     = (const int*)d_in[1];
  const float* pseudo = (const float*)d_in[2];
  const int*   slices = (const int*)d_in[3];
  const float* W1     = (const float*)d_in[4];
  const float* root1  = (const float*)d_in[5];
  const float* b1     = (const float*)d_in[6];
  const float* W2     = (const float*)d_in[7];
  const float* root2  = (const float*)d_in[8];
  const float* b2     = (const float*)d_in[9];
  const float* fcw    = (const float*)d_in[10];
  const float* fcb    = (const float*)d_in[11];
  float* out = (float*)d_out;

  float* ws   = (float*)d_ws;
  float* deg  = ws;                                  // N
  float* agg  = deg + N_NODES;                       // N*64
  float* h1   = agg + (size_t)N_NODES * 64;          // N*32
  float* h2   = h1 + (size_t)N_NODES * 32;           // N*64
  float* gbuf = h2 + (size_t)N_NODES * 64;           // 64*64
  float* T1   = gbuf + 64 * 64;                      // N*175 (dead after gemm1)
  __hip_bfloat16* Z = (__hip_bfloat16*)T1;           // 25*N*64 bf16, reuses T1 space

  // zero deg + agg + (h1,h2,gbuf harmlessly) + T1 in one contiguous memset
  size_t zero_bytes = ((size_t)N_NODES * (1 + 64 + 32 + 64 + 175) + 64 * 64) * sizeof(float);
  hipMemsetAsync(d_ws, 0, zero_bytes, stream);

  scatter1<<<N_EDGES / 8, 256, 0, stream>>>(x, ei, pseudo, T1, deg);
  gemm1<<<N_NODES / 32, 256, 0, stream>>>(T1, W1, x, root1, b1, deg, h1);
  dim3 gz(N_NODES / 256, 25);
  gemmZ<<<gz, 256, 0, stream>>>(h1, W2, Z);
  gather2<<<N_EDGES / 4, 256, 0, stream>>>(Z, ei, pseudo, agg);
  epi2<<<N_NODES / 32, 256, 0, stream>>>(agg, h1, root2, b2, deg, h2);
  pool<<<NB, 256, 0, stream>>>(h2, slices, gbuf);
  fc_ls<<<NB, 64, 0, stream>>>(gbuf, fcw, fcb, out);
}

// Round 3
// 628.991 us; speedup vs baseline: 1.7278x; 1.0898x over previous
//
#include <hip/hip_runtime.h>
#include <hip/hip_fp16.h>
#include <math.h>

#define N_NODES 51200
#define N_EDGES 819200
#define NB 64

__device__ __forceinline__ float eluf(float x) {
  return x > 0.f ? x : expm1f(x);
}

// Bilinear spline basis for edge e: 4 corners, weights + weight-matrix index.
__device__ __forceinline__ void edge_basis(const float* __restrict__ pseudo, int e,
                                           float bas[4], int kidx[4]) {
  float v0 = pseudo[2 * e] * 4.f;
  float v1 = pseudo[2 * e + 1] * 4.f;
  int lo0 = min(max((int)floorf(v0), 0), 3);
  int lo1 = min(max((int)floorf(v1), 0), 3);
  float f0 = v0 - (float)lo0, f1 = v1 - (float)lo1;
  float g0 = 1.f - f0, g1 = 1.f - f1;
  bas[0] = g0 * g1; kidx[0] = lo0 * 5 + lo1;
  bas[1] = g0 * f1; kidx[1] = lo0 * 5 + lo1 + 1;
  bas[2] = f0 * g1; kidx[2] = (lo0 + 1) * 5 + lo1;
  bas[3] = f0 * f1; kidx[3] = (lo0 + 1) * 5 + lo1 + 1;
}

// Z1[k][n][i] = sum_{j<7} x[n][j] * W1[k][j][i], fp16, k-major.
// grid: (N/256, 25), block 256.
__global__ __launch_bounds__(256) void gemmZ1(const float* __restrict__ x,
                                              const float* __restrict__ W1,
                                              __half* __restrict__ Z1) {
  __shared__ float Xs[256 * 7];
  __shared__ float Ws[7 * 32];
  int tid = threadIdx.x;
  int k = blockIdx.y;
  int n0 = blockIdx.x * 256;
  for (int idx = tid; idx < 256 * 7; idx += 256) Xs[idx] = x[(size_t)n0 * 7 + idx];
  if (tid < 224) Ws[tid] = W1[k * 224 + tid];
  __syncthreads();
  int o = tid & 31, w = tid >> 5;
  float wr[7];
#pragma unroll
  for (int j = 0; j < 7; j++) wr[j] = Ws[j * 32 + o];
  __half* zrow = Z1 + ((size_t)k * N_NODES + n0) * 32 + o;
  for (int r = w; r < 256; r += 8) {
    const float* xr = &Xs[r * 7];
    float acc = 0.f;
#pragma unroll
    for (int j = 0; j < 7; j++) acc += xr[j] * wr[j];
    zrow[(size_t)r * 32] = __float2half(acc);
  }
}

// gather1: 32 lanes per edge. msg[o] = sum_s bas_s * Z1[k_s][src][o];
// agg1[dst][o] += msg ; deg[dst] += 1 (lane 0).
__global__ __launch_bounds__(256) void gather1(const __half* __restrict__ Z1,
                                               const int* __restrict__ ei,
                                               const float* __restrict__ pseudo,
                                               float* __restrict__ agg1,
                                               float* __restrict__ deg) {
  int e = blockIdx.x * 8 + (threadIdx.x >> 5);
  int o = threadIdx.x & 31;
  int src = ei[e], dst = ei[N_EDGES + e];
  float bas[4]; int kidx[4];
  edge_basis(pseudo, e, bas, kidx);
  float m = 0.f;
#pragma unroll
  for (int s = 0; s < 4; s++)
    m += bas[s] * __half2float(Z1[((size_t)kidx[s] * N_NODES + src) * 32 + o]);
  atomicAdd(&agg1[(size_t)dst * 32 + o], m);
  if (o == 0) atomicAdd(&deg[dst], 1.f);
}

// epi1: h1 = elu(agg1/deg + x @ root1 + b1). One thread per (n,o).
__global__ __launch_bounds__(256) void epi1(const float* __restrict__ agg1,
                                            const float* __restrict__ x,
                                            const float* __restrict__ root1,
                                            const float* __restrict__ b1,
                                            const float* __restrict__ deg,
                                            float* __restrict__ h1) {
  int idx = blockIdx.x * 256 + threadIdx.x;
  int n = idx >> 5, o = idx & 31;
  float acc = agg1[idx] / fmaxf(deg[n], 1.f) + b1[o];
#pragma unroll
  for (int j = 0; j < 7; j++) acc += x[n * 7 + j] * root1[j * 32 + o];
  h1[idx] = eluf(acc);
}

// Z2[k][n][o] = sum_i h1[n][i] * W2[k][i][o], fp16, k-major.
// grid: (N/256, 25), block 256.
__global__ __launch_bounds__(256) void gemmZ2(const float* __restrict__ h1,
                                              const float* __restrict__ W2,
                                              __half* __restrict__ Z2) {
  __shared__ __align__(16) float Hs[256 * 32];
  __shared__ __align__(16) float Ws[32 * 64];
  int tid = threadIdx.x;
  int k = blockIdx.y;
  int n0 = blockIdx.x * 256;
  {
    const float4* s4 = (const float4*)(h1 + (size_t)n0 * 32);
    float4* h4 = (float4*)Hs;
    for (int idx = tid; idx < 2048; idx += 256) h4[idx] = s4[idx];
    const float4* w4 = (const float4*)(W2 + (size_t)k * 2048);
    float4* d4 = (float4*)Ws;
    for (int idx = tid; idx < 512; idx += 256) d4[idx] = w4[idx];
  }
  __syncthreads();
  int o = tid & 63, w = tid >> 6;
  float wreg[32];
#pragma unroll
  for (int i = 0; i < 32; i++) wreg[i] = Ws[i * 64 + o];
  __half* zrow = Z2 + ((size_t)k * N_NODES + n0) * 64 + o;
  for (int r = w; r < 256; r += 4) {
    const float4* hr = (const float4*)&Hs[r * 32];
    float acc = 0.f;
#pragma unroll
    for (int i4 = 0; i4 < 8; i4++) {
      float4 h = hr[i4];
      acc += h.x * wreg[i4 * 4] + h.y * wreg[i4 * 4 + 1] +
             h.z * wreg[i4 * 4 + 2] + h.w * wreg[i4 * 4 + 3];
    }
    zrow[(size_t)r * 64] = __float2half(acc);
  }
}

// gather2: one wave (64 lanes) per edge; one 64-lane atomic row add.
__global__ __launch_bounds__(256) void gather2(const __half* __restrict__ Z2,
                                               const int* __restrict__ ei,
                                               const float* __restrict__ pseudo,
                                               float* __restrict__ agg) {
  int e = blockIdx.x * 4 + (threadIdx.x >> 6);
  int o = threadIdx.x & 63;
  int src = ei[e], dst = ei[N_EDGES + e];
  float bas[4]; int kidx[4];
  edge_basis(pseudo, e, bas, kidx);
  float m = 0.f;
#pragma unroll
  for (int s = 0; s < 4; s++)
    m += bas[s] * __half2float(Z2[((size_t)kidx[s] * N_NODES + src) * 64 + o]);
  atomicAdd(&agg[(size_t)dst * 64 + o], m);
}

// epi2: h2 = elu(agg/deg + h1 @ root2 + b2). grid N/32, block 256.
__global__ __launch_bounds__(256) void epi2(const float* __restrict__ agg,
                                            const float* __restrict__ h1,
                                            const float* __restrict__ root2,
                                            const float* __restrict__ b2,
                                            const float* __restrict__ deg,
                                            float* __restrict__ h2) {
  __shared__ __align__(16) float Hs[32 * 32];
  __shared__ __align__(16) float Rs[32 * 64];
  __shared__ float Bs[64];
  int tid = threadIdx.x;
  int n0 = blockIdx.x * 32;
  {
    const float4* s4 = (const float4*)(h1 + (size_t)n0 * 32);
    float4* h4 = (float4*)Hs;
    if (tid < 256) h4[tid] = s4[tid];
    const float4* r4 = (const float4*)root2;
    float4* d4 = (float4*)Rs;
    for (int idx = tid; idx < 512; idx += 256) d4[idx] = r4[idx];
    if (tid < 64) Bs[tid] = b2[tid];
  }
  __syncthreads();
  int o = tid & 63, w = tid >> 6;
  for (int r = w; r < 32; r += 4) {
    int n = n0 + r;
    float acc = agg[(size_t)n * 64 + o] / fmaxf(deg[n], 1.f) + Bs[o];
    const float* hr = &Hs[r * 32];
#pragma unroll
    for (int i = 0; i < 32; i++) acc += hr[i] * Rs[i * 64 + o];
    h2[(size_t)n * 64 + o] = eluf(acc);
  }
}

// Mean-pool h2 over each slice range -> gbuf[g][64]
__global__ __launch_bounds__(256) void pool(const float* __restrict__ h2,
                                            const int* __restrict__ slices,
                                            float* __restrict__ gbuf) {
  int g = blockIdx.x;
  int tid = threadIdx.x;
  int o = tid & 63, q = tid >> 6;
  int s0 = slices[g], s1 = slices[g + 1];
  float p = 0.f;
  for (int n = s0 + q; n < s1; n += 4) p += h2[(size_t)n * 64 + o];
  __shared__ float red[4][64];
  red[q][o] = p;
  __syncthreads();
  if (q == 0) {
    float s = red[0][o] + red[1][o] + red[2][o] + red[3][o];
    float cnt = (float)(s1 - s0);
    gbuf[g * 64 + o] = s / fmaxf(cnt, 1.f);
  }
}

// FC(64->30) + log_softmax. One block (64 thr) per group; lanes 0..29 active.
__global__ __launch_bounds__(64) void fc_ls(const float* __restrict__ gbuf,
                                            const float* __restrict__ fcw,
                                            const float* __restrict__ fcb,
                                            float* __restrict__ out) {
  int g = blockIdx.x;
  int l = threadIdx.x;
  float logit = -INFINITY;
  if (l < 30) {
    float acc = fcb[l];
    for (int i = 0; i < 64; i++) acc += gbuf[g * 64 + i] * fcw[i * 30 + l];
    logit = acc;
  }
  float m = logit;
  for (int off = 16; off; off >>= 1) m = fmaxf(m, __shfl_xor(m, off, 32));
  float e = (l < 30) ? expf(logit - m) : 0.f;
  for (int off = 16; off; off >>= 1) e += __shfl_xor(e, off, 32);
  if (l < 30) out[g * 30 + l] = logit - m - logf(e);
}

extern "C" void kernel_launch(void* const* d_in, const int* in_sizes, int n_in,
                              void* d_out, int out_size, void* d_ws, size_t ws_size,
                              hipStream_t stream) {
  const float* x      = (const float*)d_in[0];
  const int*   ei     = (const int*)d_in[1];
  const float* pseudo = (const float*)d_in[2];
  const int*   slices = (const int*)d_in[3];
  const float* W1     = (const float*)d_in[4];
  const float* root1  = (const float*)d_in[5];
  const float* b1     = (const float*)d_in[6];
  const float* W2     = (const float*)d_in[7];
  const float* root2  = (const float*)d_in[8];
  const float* b2     = (const float*)d_in[9];
  const float* fcw    = (const float*)d_in[10];
  const float* fcb    = (const float*)d_in[11];
  float* out = (float*)d_out;

  float* ws   = (float*)d_ws;
  float* deg  = ws;                                  // N
  float* agg1 = deg + N_NODES;                       // N*32
  float* agg  = agg1 + (size_t)N_NODES * 32;         // N*64
  float* h1   = agg + (size_t)N_NODES * 64;          // N*32
  float* h2   = h1 + (size_t)N_NODES * 32;           // N*64
  float* gbuf = h2 + (size_t)N_NODES * 64;           // 64*64
  __half* Z   = (__half*)(gbuf + 64 * 64);           // 25*N*64 fp16 (Z1 uses 25*N*32)

  // zero deg + agg1 + agg (contiguous at ws start)
  size_t zero_bytes = (size_t)N_NODES * (1 + 32 + 64) * sizeof(float);
  hipMemsetAsync(d_ws, 0, zero_bytes, stream);

  dim3 gz(N_NODES / 256, 25);
  gemmZ1<<<gz, 256, 0, stream>>>(x, W1, Z);
  gather1<<<N_EDGES / 8, 256, 0, stream>>>(Z, ei, pseudo, agg1, deg);
  epi1<<<N_NODES * 32 / 256, 256, 0, stream>>>(agg1, x, root1, b1, deg, h1);
  gemmZ2<<<gz, 256, 0, stream>>>(h1, W2, Z);
  gather2<<<N_EDGES / 4, 256, 0, stream>>>(Z, ei, pseudo, agg);
  epi2<<<N_NODES / 32, 256, 0, stream>>>(agg, h1, root2, b2, deg, h2);
  pool<<<NB, 256, 0, stream>>>(h2, slices, gbuf);
  fc_ls<<<NB, 64, 0, stream>>>(gbuf, fcw, fcb, out);
}

// Round 4
// 579.028 us; speedup vs baseline: 1.8769x; 1.0863x over previous
//
#include <hip/hip_runtime.h>
#include <hip/hip_fp16.h>
#include <math.h>

#define N_NODES 51200
#define N_EDGES 819200
#define NB 64
#define CAP 64  // max in-degree capacity; Binomial(E,1/N) mean 16, P(>=64) ~ 1e-19

__device__ __forceinline__ float eluf(float x) {
  return x > 0.f ? x : expm1f(x);
}

// Build dst-CSR with fixed-capacity buckets. cnt doubles as degree.
__global__ __launch_bounds__(256) void scatter_eid(const int* __restrict__ ei,
                                                   int* __restrict__ cnt,
                                                   int* __restrict__ bucket) {
  int e = blockIdx.x * 256 + threadIdx.x;
  int dst = ei[N_EDGES + e];
  int slot = atomicAdd(&cnt[dst], 1);
  if (slot < CAP) bucket[dst * CAP + slot] = e;
}

// Z1[(n*25 + k)*32 + i] = sum_{j<7} x[n][j] * W1[k][j][i], fp16, n-major.
__global__ __launch_bounds__(256) void gemmZ1(const float* __restrict__ x,
                                              const float* __restrict__ W1,
                                              __half* __restrict__ Z1) {
  __shared__ float Xs[256 * 7];
  __shared__ float Ws[7 * 32];
  int tid = threadIdx.x;
  int k = blockIdx.y;
  int n0 = blockIdx.x * 256;
  for (int idx = tid; idx < 1792; idx += 256) Xs[idx] = x[(size_t)n0 * 7 + idx];
  if (tid < 224) Ws[tid] = W1[k * 224 + tid];
  __syncthreads();
  int o = tid & 31, w = tid >> 5;
  float wr[7];
#pragma unroll
  for (int j = 0; j < 7; j++) wr[j] = Ws[j * 32 + o];
  for (int r = w; r < 256; r += 8) {
    const float* xr = &Xs[r * 7];
    float acc = 0.f;
#pragma unroll
    for (int j = 0; j < 7; j++) acc += xr[j] * wr[j];
    Z1[((size_t)(n0 + r) * 25 + k) * 32 + o] = __float2half(acc);
  }
}

// gather1: one wave per node, 2 edges per iteration (lane = j2*32 + o).
// h1[n][o] = elu( (1/deg) * sum_e bas * Z1[src] + x[n] @ root1 + b1 )
__global__ __launch_bounds__(256) void gather1(const __half* __restrict__ Z1,
                                               const int* __restrict__ ei,
                                               const float* __restrict__ pseudo,
                                               const int* __restrict__ cnt,
                                               const int* __restrict__ bucket,
                                               const float* __restrict__ x,
                                               const float* __restrict__ root1,
                                               const float* __restrict__ b1,
                                               float* __restrict__ h1) {
  __shared__ float Rs[224];
  __shared__ float Bs[32];
  int tid = threadIdx.x;
  if (tid < 224) Rs[tid] = root1[tid];
  if (tid < 32) Bs[tid] = b1[tid];
  __syncthreads();
  int n = blockIdx.x * 4 + (tid >> 6);
  int l = tid & 63, o = l & 31, j2 = l >> 5;
  int deg = cnt[n];
  int degc = min(deg, CAP);
  float m = 0.f;
  for (int j = 0; j < degc; j += 2) {
    if (j + j2 < degc) {
      int eid = bucket[n * CAP + j + j2];
      int src = ei[eid];
      float v0 = pseudo[2 * eid] * 4.f;
      float v1 = pseudo[2 * eid + 1] * 4.f;
      int lo0 = min(max((int)floorf(v0), 0), 3);
      int lo1 = min(max((int)floorf(v1), 0), 3);
      float f0 = v0 - (float)lo0, f1 = v1 - (float)lo1;
      float g0 = 1.f - f0, g1 = 1.f - f1;
      const __half* zb = Z1 + ((size_t)src * 25 + lo0 * 5 + lo1) * 32 + o;
      m += g0 * g1 * __half2float(zb[0]);
      m += g0 * f1 * __half2float(zb[32]);
      m += f0 * g1 * __half2float(zb[160]);
      m += f0 * f1 * __half2float(zb[192]);
    }
  }
  m += __shfl_xor(m, 32);
  if (j2 == 0) {
    float acc = m / fmaxf((float)deg, 1.f) + Bs[o];
    const float* xr = x + (size_t)n * 7;
#pragma unroll
    for (int j = 0; j < 7; j++) acc += xr[j] * Rs[j * 32 + o];
    h1[(size_t)n * 32 + o] = eluf(acc);
  }
}

// Z2[(n*25 + k)*64 + o] = sum_i h1[n][i] * W2[k][i][o], fp16, n-major.
__global__ __launch_bounds__(256) void gemmZ2(const float* __restrict__ h1,
                                              const float* __restrict__ W2,
                                              __half* __restrict__ Z2) {
  __shared__ __align__(16) float Hs[256 * 32];
  __shared__ __align__(16) float Ws[32 * 64];
  int tid = threadIdx.x;
  int k = blockIdx.y;
  int n0 = blockIdx.x * 256;
  {
    const float4* s4 = (const float4*)(h1 + (size_t)n0 * 32);
    float4* h4 = (float4*)Hs;
    for (int idx = tid; idx < 2048; idx += 256) h4[idx] = s4[idx];
    const float4* w4 = (const float4*)(W2 + (size_t)k * 2048);
    float4* d4 = (float4*)Ws;
    for (int idx = tid; idx < 512; idx += 256) d4[idx] = w4[idx];
  }
  __syncthreads();
  int o = tid & 63, w = tid >> 6;
  float wreg[32];
#pragma unroll
  for (int i = 0; i < 32; i++) wreg[i] = Ws[i * 64 + o];
  for (int r = w; r < 256; r += 4) {
    const float4* hr = (const float4*)&Hs[r * 32];
    float acc = 0.f;
#pragma unroll
    for (int i4 = 0; i4 < 8; i4++) {
      float4 h = hr[i4];
      acc += h.x * wreg[i4 * 4] + h.y * wreg[i4 * 4 + 1] +
             h.z * wreg[i4 * 4 + 2] + h.w * wreg[i4 * 4 + 3];
    }
    Z2[((size_t)(n0 + r) * 25 + k) * 64 + o] = __float2half(acc);
  }
}

// gather2: one wave per node, 64 lanes = 64 features, epilogue fused.
__global__ __launch_bounds__(256) void gather2(const __half* __restrict__ Z2,
                                               const int* __restrict__ ei,
                                               const float* __restrict__ pseudo,
                                               const int* __restrict__ cnt,
                                               const int* __restrict__ bucket,
                                               const float* __restrict__ h1,
                                               const float* __restrict__ root2,
                                               const float* __restrict__ b2,
                                               float* __restrict__ h2) {
  __shared__ __align__(16) float Rs[32 * 64];
  __shared__ float Bs[64];
  int tid = threadIdx.x;
  {
    const float4* r4 = (const float4*)root2;
    float4* d4 = (float4*)Rs;
    for (int idx = tid; idx < 512; idx += 256) d4[idx] = r4[idx];
    if (tid < 64) Bs[tid] = b2[tid];
  }
  __syncthreads();
  int n = blockIdx.x * 4 + (tid >> 6);
  int o = tid & 63;
  int deg = cnt[n];
  int degc = min(deg, CAP);
  float m = 0.f;
  for (int j = 0; j < degc; j++) {
    int eid = bucket[n * CAP + j];
    int src = ei[eid];
    float v0 = pseudo[2 * eid] * 4.f;
    float v1 = pseudo[2 * eid + 1] * 4.f;
    int lo0 = min(max((int)floorf(v0), 0), 3);
    int lo1 = min(max((int)floorf(v1), 0), 3);
    float f0 = v0 - (float)lo0, f1 = v1 - (float)lo1;
    float g0 = 1.f - f0, g1 = 1.f - f1;
    const __half* zb = Z2 + ((size_t)src * 25 + lo0 * 5 + lo1) * 64 + o;
    m += g0 * g1 * __half2float(zb[0]);
    m += g0 * f1 * __half2float(zb[64]);
    m += f0 * g1 * __half2float(zb[320]);
    m += f0 * f1 * __half2float(zb[384]);
  }
  float acc = m / fmaxf((float)deg, 1.f) + Bs[o];
  const float* hr = h1 + (size_t)n * 32;
#pragma unroll
  for (int i = 0; i < 32; i++) acc += hr[i] * Rs[i * 64 + o];
  h2[(size_t)n * 64 + o] = eluf(acc);
}

// Mean-pool h2 over each slice range -> gbuf[g][64]
__global__ __launch_bounds__(256) void pool(const float* __restrict__ h2,
                                            const int* __restrict__ slices,
                                            float* __restrict__ gbuf) {
  int g = blockIdx.x;
  int tid = threadIdx.x;
  int o = tid & 63, q = tid >> 6;
  int s0 = slices[g], s1 = slices[g + 1];
  float p = 0.f;
  for (int n = s0 + q; n < s1; n += 4) p += h2[(size_t)n * 64 + o];
  __shared__ float red[4][64];
  red[q][o] = p;
  __syncthreads();
  if (q == 0) {
    float s = red[0][o] + red[1][o] + red[2][o] + red[3][o];
    float cnt2 = (float)(s1 - s0);
    gbuf[g * 64 + o] = s / fmaxf(cnt2, 1.f);
  }
}

// FC(64->30) + log_softmax. One block (64 thr) per group; lanes 0..29 active.
__global__ __launch_bounds__(64) void fc_ls(const float* __restrict__ gbuf,
                                            const float* __restrict__ fcw,
                                            const float* __restrict__ fcb,
                                            float* __restrict__ out) {
  int g = blockIdx.x;
  int l = threadIdx.x;
  float logit = -INFINITY;
  if (l < 30) {
    float acc = fcb[l];
    for (int i = 0; i < 64; i++) acc += gbuf[g * 64 + i] * fcw[i * 30 + l];
    logit = acc;
  }
  float m = logit;
  for (int off = 16; off; off >>= 1) m = fmaxf(m, __shfl_xor(m, off, 32));
  float e = (l < 30) ? expf(logit - m) : 0.f;
  for (int off = 16; off; off >>= 1) e += __shfl_xor(e, off, 32);
  if (l < 30) out[g * 30 + l] = logit - m - logf(e);
}

extern "C" void kernel_launch(void* const* d_in, const int* in_sizes, int n_in,
                              void* d_out, int out_size, void* d_ws, size_t ws_size,
                              hipStream_t stream) {
  const float* x      = (const float*)d_in[0];
  const int*   ei     = (const int*)d_in[1];
  const float* pseudo = (const float*)d_in[2];
  const int*   slices = (const int*)d_in[3];
  const float* W1     = (const float*)d_in[4];
  const float* root1  = (const float*)d_in[5];
  const float* b1     = (const float*)d_in[6];
  const float* W2     = (const float*)d_in[7];
  const float* root2  = (const float*)d_in[8];
  const float* b2     = (const float*)d_in[9];
  const float* fcw    = (const float*)d_in[10];
  const float* fcb    = (const float*)d_in[11];
  float* out = (float*)d_out;

  char* ws = (char*)d_ws;
  int*   cnt    = (int*)ws;                                   // N ints
  int*   bucket = cnt + N_NODES;                              // N*CAP ints (13.1 MB)
  float* h1     = (float*)(bucket + (size_t)N_NODES * CAP);   // N*32
  float* h2     = h1 + (size_t)N_NODES * 32;                  // N*64
  float* gbuf   = h2 + (size_t)N_NODES * 64;                  // 64*64
  __half* Z     = (__half*)(gbuf + 64 * 64);                  // 25*N*64 fp16 (164 MB)

  // only cnt needs zeroing (200 KB)
  hipMemsetAsync(cnt, 0, N_NODES * sizeof(int), stream);

  scatter_eid<<<N_EDGES / 256, 256, 0, stream>>>(ei, cnt, bucket);
  dim3 gz(N_NODES / 256, 25);
  gemmZ1<<<gz, 256, 0, stream>>>(x, W1, Z);
  gather1<<<N_NODES / 4, 256, 0, stream>>>(Z, ei, pseudo, cnt, bucket, x, root1, b1, h1);
  gemmZ2<<<gz, 256, 0, stream>>>(h1, W2, Z);
  gather2<<<N_NODES / 4, 256, 0, stream>>>(Z, ei, pseudo, cnt, bucket, h1, root2, b2, h2);
  pool<<<NB, 256, 0, stream>>>(h2, slices, gbuf);
  fc_ls<<<NB, 64, 0, stream>>>(gbuf, fcw, fcb, out);
}

// Round 5
// 576.939 us; speedup vs baseline: 1.8837x; 1.0036x over previous
//
#include <hip/hip_runtime.h>
#include <hip/hip_fp16.h>
#include <math.h>

#define N_NODES 51200
#define N_EDGES 819200
#define NB 64
#define CAP 64  // max in-degree capacity; Binomial(E,1/N) mean 16, P(>=64) ~ 1e-19

__device__ __forceinline__ float eluf(float x) {
  return x > 0.f ? x : expm1f(x);
}

// Build dst-CSR with fixed-capacity buckets; pack {src|K<<16, half2(f0,f1)}.
// cnt doubles as degree.
__global__ __launch_bounds__(256) void scatter_eid(const int* __restrict__ ei,
                                                   const float* __restrict__ pseudo,
                                                   int* __restrict__ cnt,
                                                   int2* __restrict__ bucket) {
  int e = blockIdx.x * 256 + threadIdx.x;
  int src = ei[e], dst = ei[N_EDGES + e];
  float v0 = pseudo[2 * e] * 4.f;
  float v1 = pseudo[2 * e + 1] * 4.f;
  int lo0 = min(max((int)floorf(v0), 0), 3);
  int lo1 = min(max((int)floorf(v1), 0), 3);
  float f0 = v0 - (float)lo0, f1 = v1 - (float)lo1;
  int K = lo0 * 5 + lo1;  // corners at K, K+1, K+5, K+6
  unsigned short u0 = __half_as_ushort(__float2half(f0));
  unsigned short u1 = __half_as_ushort(__float2half(f1));
  int w0 = src | (K << 16);
  int w1 = (int)((unsigned)u0 | ((unsigned)u1 << 16));
  int slot = atomicAdd(&cnt[dst], 1);
  if (slot < CAP) bucket[(size_t)dst * CAP + slot] = make_int2(w0, w1);
}

// Layer 1 fused: per block, T[32 nodes][175] in LDS (no atomics), then
// h1 = elu( (T @ W1)/deg + x @ root1 + b1 ).
#define L1_NODES 32
__global__ __launch_bounds__(256) void fused_l1(const int2* __restrict__ bucket,
                                                const int* __restrict__ cnt,
                                                const float* __restrict__ x,
                                                const float* __restrict__ W1,
                                                const float* __restrict__ root1,
                                                const float* __restrict__ b1,
                                                float* __restrict__ h1) {
  __shared__ float T[L1_NODES * 175];
  int tid = threadIdx.x;
  int n0 = blockIdx.x * L1_NODES;
  for (int idx = tid; idx < L1_NODES * 175; idx += 256) T[idx] = 0.f;
  __syncthreads();
  // Phase A: wave wv handles nodes wv, wv+4, ... Lane l<32: s=l>>3 (corner),
  // i=l&7 (feature, i<7 active). All 28 active addresses distinct -> race-free.
  int wv = tid >> 6, l = tid & 63;
  int s = (l >> 3) & 3, i = l & 7;
  bool act = (l < 32) && (i < 7);
  for (int nn = wv; nn < L1_NODES; nn += 4) {
    int n = n0 + nn;
    int dg = min(cnt[n], CAP);
    float* Tn = &T[nn * 175];
    const int2* bk = bucket + (size_t)n * CAP;
#pragma unroll 2
    for (int j = 0; j < dg; j++) {
      int2 rec = bk[j];
      int src = rec.x & 0xFFFF, K = rec.x >> 16;
      unsigned pv = (unsigned)rec.y;
      float f0 = __half2float(__ushort_as_half((unsigned short)(pv & 0xFFFF)));
      float f1 = __half2float(__ushort_as_half((unsigned short)(pv >> 16)));
      if (act) {
        float b0 = (s & 2) ? f0 : 1.f - f0;
        float bw = (s & 1) ? f1 : 1.f - f1;
        int ko = K + (s >> 1) * 5 + (s & 1);
        Tn[ko * 7 + i] += b0 * bw * x[src * 7 + i];
      }
    }
  }
  __syncthreads();
  // Phase B: thread (o, g): 4 nodes g, g+8, g+16, g+24; W1 from L1 cache.
  int o = tid & 31, g = tid >> 5;
  float acc[4] = {0.f, 0.f, 0.f, 0.f};
  for (int kk = 0; kk < 175; kk++) {
    float w = W1[kk * 32 + o];
#pragma unroll
    for (int q = 0; q < 4; q++) acc[q] += T[(g + q * 8) * 175 + kk] * w;
  }
#pragma unroll
  for (int q = 0; q < 4; q++) {
    int n = n0 + g + q * 8;
    float dv = fmaxf((float)cnt[n], 1.f);
    float v = acc[q] / dv + b1[o];
    const float* xr = x + (size_t)n * 7;
#pragma unroll
    for (int jj = 0; jj < 7; jj++) v += xr[jj] * root1[jj * 32 + o];
    h1[(size_t)n * 32 + o] = eluf(v);
  }
}

// Layer 2 fused: per block, T[16 nodes][800] in LDS (51.2 KB), then
// h2 = elu( (T @ W2)/deg + h1 @ root2 + b2 ).
#define L2_NODES 16
__global__ __launch_bounds__(256) void fused_l2(const int2* __restrict__ bucket,
                                                const int* __restrict__ cnt,
                                                const float* __restrict__ h1,
                                                const float* __restrict__ W2,
                                                const float* __restrict__ root2,
                                                const float* __restrict__ b2,
                                                float* __restrict__ h2) {
  __shared__ float T[L2_NODES * 800];   // 51.2 KB
  __shared__ float Hs[L2_NODES * 32];   // block's own h1 rows (for root term)
  __shared__ float Rs[32 * 64];
  __shared__ float Bs[64];
  int tid = threadIdx.x;
  int n0 = blockIdx.x * L2_NODES;
  {
    float4* t4 = (float4*)T;
    for (int idx = tid; idx < L2_NODES * 200; idx += 256)
      t4[idx] = float4{0.f, 0.f, 0.f, 0.f};
    const float4* s4 = (const float4*)(h1 + (size_t)n0 * 32);
    float4* h4 = (float4*)Hs;
    if (tid < L2_NODES * 8) h4[tid] = s4[tid];
    const float4* r4 = (const float4*)root2;
    float4* d4 = (float4*)Rs;
    for (int idx = tid; idx < 512; idx += 256) d4[idx] = r4[idx];
    if (tid < 64) Bs[tid] = b2[tid];
  }
  __syncthreads();
  // Phase A: wave wv -> nodes wv, wv+4, ...; lane: i=l&31 (feature),
  // s2=l>>5 (corner pair). Corner planes {K,K+1} and {K+5,K+6} are disjoint
  // and distinct per half-wave -> all 64 lane-addresses distinct -> race-free.
  int wv = tid >> 6, l = tid & 63;
  int i = l & 31, s2 = l >> 5;
  for (int nn = wv; nn < L2_NODES; nn += 4) {
    int n = n0 + nn;
    int dg = min(cnt[n], CAP);
    float* Tn = &T[nn * 800];
    const int2* bk = bucket + (size_t)n * CAP;
#pragma unroll 2
    for (int j = 0; j < dg; j++) {
      int2 rec = bk[j];
      int src = rec.x & 0xFFFF, K = rec.x >> 16;
      unsigned pv = (unsigned)rec.y;
      float f0 = __half2float(__ushort_as_half((unsigned short)(pv & 0xFFFF)));
      float f1 = __half2float(__ushort_as_half((unsigned short)(pv >> 16)));
      float hv = h1[(size_t)src * 32 + i];
      float bc = s2 ? f1 : (1.f - f1);
      float* ta = &Tn[(K + s2) * 32 + i];
      float* tb = &Tn[(K + 5 + s2) * 32 + i];
      float va = *ta + (1.f - f0) * bc * hv;
      float vb = *tb + f0 * bc * hv;
      *ta = va;
      *tb = vb;
    }
  }
  __syncthreads();
  // Phase B: thread (o, g): nodes g, g+4, g+8, g+12. Within a wave g is
  // uniform -> T reads are broadcasts; W2 reads coalesced from L2.
  int o = tid & 63, g = tid >> 6;
  float acc[4] = {0.f, 0.f, 0.f, 0.f};
  for (int k4 = 0; k4 < 200; k4++) {
    float4 tv[4];
#pragma unroll
    for (int q = 0; q < 4; q++)
      tv[q] = *(const float4*)&T[(g + q * 4) * 800 + k4 * 4];
#pragma unroll
    for (int jj = 0; jj < 4; jj++) {
      float w = W2[(k4 * 4 + jj) * 64 + o];
      acc[0] += ((const float*)&tv[0])[jj] * w;
      acc[1] += ((const float*)&tv[1])[jj] * w;
      acc[2] += ((const float*)&tv[2])[jj] * w;
      acc[3] += ((const float*)&tv[3])[jj] * w;
    }
  }
#pragma unroll
  for (int q = 0; q < 4; q++) {
    int nn = g + q * 4, n = n0 + nn;
    float dv = fmaxf((float)cnt[n], 1.f);
    float v = acc[q] / dv + Bs[o];
    const float* hr = &Hs[nn * 32];
#pragma unroll
    for (int ii = 0; ii < 32; ii++) v += hr[ii] * Rs[ii * 64 + o];
    h2[(size_t)n * 64 + o] = eluf(v);
  }
}

// Mean-pool h2 over each slice range -> gbuf[g][64]
__global__ __launch_bounds__(256) void pool(const float* __restrict__ h2,
                                            const int* __restrict__ slices,
                                            float* __restrict__ gbuf) {
  int g = blockIdx.x;
  int tid = threadIdx.x;
  int o = tid & 63, q = tid >> 6;
  int s0 = slices[g], s1 = slices[g + 1];
  float p = 0.f;
  for (int n = s0 + q; n < s1; n += 4) p += h2[(size_t)n * 64 + o];
  __shared__ float red[4][64];
  red[q][o] = p;
  __syncthreads();
  if (q == 0) {
    float s = red[0][o] + red[1][o] + red[2][o] + red[3][o];
    float cnt2 = (float)(s1 - s0);
    gbuf[g * 64 + o] = s / fmaxf(cnt2, 1.f);
  }
}

// FC(64->30) + log_softmax. One block (64 thr) per group; lanes 0..29 active.
__global__ __launch_bounds__(64) void fc_ls(const float* __restrict__ gbuf,
                                            const float* __restrict__ fcw,
                                            const float* __restrict__ fcb,
                                            float* __restrict__ out) {
  int g = blockIdx.x;
  int l = threadIdx.x;
  float logit = -INFINITY;
  if (l < 30) {
    float acc = fcb[l];
    for (int i = 0; i < 64; i++) acc += gbuf[g * 64 + i] * fcw[i * 30 + l];
    logit = acc;
  }
  float m = logit;
  for (int off = 16; off; off >>= 1) m = fmaxf(m, __shfl_xor(m, off, 32));
  float e = (l < 30) ? expf(logit - m) : 0.f;
  for (int off = 16; off; off >>= 1) e += __shfl_xor(e, off, 32);
  if (l < 30) out[g * 30 + l] = logit - m - logf(e);
}

extern "C" void kernel_launch(void* const* d_in, const int* in_sizes, int n_in,
                              void* d_out, int out_size, void* d_ws, size_t ws_size,
                              hipStream_t stream) {
  const float* x      = (const float*)d_in[0];
  const int*   ei     = (const int*)d_in[1];
  const float* pseudo = (const float*)d_in[2];
  const int*   slices = (const int*)d_in[3];
  const float* W1     = (const float*)d_in[4];
  const float* root1  = (const float*)d_in[5];
  const float* b1     = (const float*)d_in[6];
  const float* W2     = (const float*)d_in[7];
  const float* root2  = (const float*)d_in[8];
  const float* b2     = (const float*)d_in[9];
  const float* fcw    = (const float*)d_in[10];
  const float* fcb    = (const float*)d_in[11];
  float* out = (float*)d_out;

  char* ws = (char*)d_ws;
  int*   cnt    = (int*)ws;                                    // N ints
  int2*  bucket = (int2*)(cnt + N_NODES);                      // N*CAP int2 (26.2 MB)
  float* h1     = (float*)(bucket + (size_t)N_NODES * CAP);    // N*32
  float* h2     = h1 + (size_t)N_NODES * 32;                   // N*64
  float* gbuf   = h2 + (size_t)N_NODES * 64;                   // 64*64

  hipMemsetAsync(cnt, 0, N_NODES * sizeof(int), stream);

  scatter_eid<<<N_EDGES / 256, 256, 0, stream>>>(ei, pseudo, cnt, bucket);
  fused_l1<<<N_NODES / L1_NODES, 256, 0, stream>>>(bucket, cnt, x, W1, root1, b1, h1);
  fused_l2<<<N_NODES / L2_NODES, 256, 0, stream>>>(bucket, cnt, h1, W2, root2, b2, h2);
  pool<<<NB, 256, 0, stream>>>(h2, slices, gbuf);
  fc_ls<<<NB, 64, 0, stream>>>(gbuf, fcw, fcb, out);
}